// Round 19
// baseline (567.558 us; speedup 1.0000x reference)
//
#include <hip/hip_runtime.h>

#define NN 100000
#define EE 1600000
#define EPSV 1e-5f
#define QW 12500  // nodes per XCD stripe (8 * 12500 = 100000)

using short8 = __attribute__((ext_vector_type(8))) short;
using floatx4 = __attribute__((ext_vector_type(4))) float;

// fp32 -> bf16 round-to-nearest-even
__device__ __forceinline__ unsigned short f2bf(float f) {
    union { float f; unsigned int u; } cv;
    cv.f = f;
    unsigned int u = cv.u;
    u += 0x7FFFu + ((u >> 16) & 1u);
    return (unsigned short)(u >> 16);
}

__device__ __forceinline__ float bf2f(unsigned short u) {
    union { unsigned int i; float f; } cv;
    cv.i = ((unsigned int)u) << 16;
    return cv.f;
}

// ================= degree histogram: per-XCD private copies ===================
__global__ void deg_kernel(const int* __restrict__ dst, int* __restrict__ degi8) {
    int e = blockIdx.x * 256 + threadIdx.x;
    if (e >= EE) return;
    int q = blockIdx.x & 7;
    atomicAdd(&degi8[q * NN + dst[e]], 1);
}

// ================= scan1: sum 8 histogram copies + dinv + block-local prefix ==
__global__ void scan1(const int* __restrict__ degi8, int* __restrict__ degi,
                      int* __restrict__ offsets, int* __restrict__ partial,
                      float* __restrict__ dinv) {
    __shared__ int sdata[256];
    int t = threadIdx.x;
    int n = blockIdx.x * 256 + t;
    int v = 0;
    if (n < NN) {
#pragma unroll
        for (int q = 0; q < 8; ++q) v += degi8[q * NN + n];
        degi[n] = v;
        dinv[n] = rsqrtf((float)v + 1.0f);
    }
    sdata[t] = v;
    __syncthreads();
    for (int off = 1; off < 256; off <<= 1) {
        int x = (t >= off) ? sdata[t - off] : 0;
        __syncthreads();
        sdata[t] += x;
        __syncthreads();
    }
    if (n < NN) offsets[n] = sdata[t] - v;  // block-local exclusive
    if (t == 255) partial[blockIdx.x] = sdata[255];
}

// ================= scan2 + fused stats zeroing ================================
__global__ void scan2(int* __restrict__ partial, int* __restrict__ partial_pref,
                      int nparts, float* __restrict__ stats) {
    __shared__ int sdata[512];
    int t = threadIdx.x;
    if (t < 384) stats[t] = 0.f;
    int v = (t < nparts) ? partial[t] : 0;
    sdata[t] = v;
    __syncthreads();
    for (int off = 1; off < 512; off <<= 1) {
        int x = (t >= off) ? sdata[t - off] : 0;
        __syncthreads();
        sdata[t] += x;
        __syncthreads();
    }
    if (t < nparts) partial_pref[t] = sdata[t] - v;  // exclusive
}

// ================= CSR fill, XCD-sharded by dst range =========================
__global__ void fill_kernel(const int* __restrict__ src, const int* __restrict__ dst,
                            int* __restrict__ offsets,
                            const int* __restrict__ partial_pref,
                            const float* __restrict__ dinv,
                            int2* __restrict__ sorted) {
    int q = blockIdx.x & 7;
    int e = (blockIdx.x >> 3) * 256 + threadIdx.x;
    if (e >= EE) return;
    int d = dst[e];
    if ((unsigned)(d - q * QW) >= (unsigned)QW) return;
    int s = src[e];
    int idx = partial_pref[d >> 8] + atomicAdd(&offsets[d], 1);
    int2 rec;
    rec.x = s;
    rec.y = __float_as_int(dinv[s] * dinv[d]);
    sorted[idx] = rec;
}

// ================= hw(bf16) = act(in) @ W via MFMA bf16 ======================
__global__ __launch_bounds__(256) void gemm64_bn(const float* __restrict__ in,
                                                 const float* __restrict__ x,
                                                 const float* __restrict__ Win,
                                                 const float* __restrict__ bin,
                                                 const float* __restrict__ stats,
                                                 const float* __restrict__ gamma,
                                                 const float* __restrict__ beta,
                                                 const float* __restrict__ W,
                                                 unsigned short* __restrict__ out,
                                                 int mode) {
    __shared__ __align__(16) unsigned short As[64 * 72];
    __shared__ __align__(16) unsigned short Wt[64 * 72];
    __shared__ float scale[64], shift[64];
    __shared__ float Wins[320];
    __shared__ float bins[64];
    int t = threadIdx.x;
    if (mode == 1) {
        if (t < 64) {
            const float invN = 1.0f / (float)NN;
            float mean = stats[t] * invN;
            float var = stats[64 + t] * invN - mean * mean;
            float rstd = rsqrtf(var + EPSV);
            float sc = gamma[t] * rstd;
            scale[t] = sc;
            shift[t] = beta[t] - mean * sc;
        }
    } else {
        for (int i = t; i < 320; i += 256) Wins[i] = Win[i];
        if (t < 64) bins[t] = bin[t];
    }
    for (int i = t; i < 4096; i += 256) {
        int k = i >> 6, c = i & 63;
        Wt[c * 72 + k] = f2bf(W[k * 64 + c]);
    }
    __syncthreads();
    int base = blockIdx.x * 64;
    if (mode == 1) {
        for (int i = t; i < 4096; i += 256) {
            int r = i >> 6, c = i & 63;
            float v = 0.f;
            if (base + r < NN) {
                v = in[(base + r) * 64 + c];
                v = fmaxf(v * scale[c] + shift[c], 0.f);
            }
            As[r * 72 + c] = f2bf(v);
        }
    } else {
        for (int i = t; i < 4096; i += 256) {
            int r = i >> 6, c = i & 63;
            int n = base + r;
            float v = 0.f;
            if (n < NN) {
                float acc = bins[c];
#pragma unroll
                for (int k = 0; k < 5; ++k) acc += x[n * 5 + k] * Wins[k * 64 + c];
                v = fmaxf(acc, 0.f);
            }
            As[r * 72 + c] = f2bf(v);
        }
    }
    __syncthreads();
    int wv = t >> 6;
    int lane = t & 63;
    int quad = lane >> 4;
    int mm = lane & 15;
    short8 a0 = *(const short8*)&As[(wv * 16 + mm) * 72 + quad * 8];
    short8 a1 = *(const short8*)&As[(wv * 16 + mm) * 72 + 32 + quad * 8];
#pragma unroll
    for (int ct = 0; ct < 4; ++ct) {
        short8 b0 = *(const short8*)&Wt[(ct * 16 + mm) * 72 + quad * 8];
        short8 b1 = *(const short8*)&Wt[(ct * 16 + mm) * 72 + 32 + quad * 8];
        floatx4 acc = {0.f, 0.f, 0.f, 0.f};
        acc = __builtin_amdgcn_mfma_f32_16x16x32_bf16(a0, b0, acc, 0, 0, 0);
        acc = __builtin_amdgcn_mfma_f32_16x16x32_bf16(a1, b1, acc, 0, 0, 0);
#pragma unroll
        for (int reg = 0; reg < 4; ++reg) {
            int n = base + wv * 16 + quad * 4 + reg;
            if (n < NN) out[n * 64 + ct * 16 + mm] = f2bf(acc[reg]);
        }
    }
}

// ================= CSR gather aggregation, 2 edges/wave + metadata prefetch ===
__global__ __launch_bounds__(256) void agg_kernel(const unsigned int* __restrict__ hw32,
                                                  const int2* __restrict__ sorted,
                                                  const int* __restrict__ offsets,
                                                  const int* __restrict__ partial_pref,
                                                  const int* __restrict__ degi,
                                                  const float* __restrict__ dinv,
                                                  const float* __restrict__ b,
                                                  float* __restrict__ agg,
                                                  float* __restrict__ stats) {
    int t = threadIdx.x;
    int lane = t & 63;
    int w = t >> 6;
    int half = lane >> 5;
    int c2 = lane & 31;  // channel pair: 2*c2, 2*c2+1
    const int stride = gridDim.x * 4;
    float b0 = b[2 * c2], b1v = b[2 * c2 + 1];
    float bsx = 0.f, bsy = 0.f, bqx = 0.f, bqy = 0.f;
    int n0 = blockIdx.x * 4 + w;
    // metadata prefetch state for node n (loaded one iteration ahead)
    int pf_cnt = 0, pf_end = 0, pf_pref = 0;
    float pf_di = 0.f;
    if (n0 < NN) {
        pf_cnt = degi[n0];
        pf_end = offsets[n0];
        pf_pref = partial_pref[n0 >> 8];
        pf_di = dinv[n0];
    }
    for (int n = n0; n < NN; n += stride) {
        int cnt = pf_cnt;
        int start = pf_pref + pf_end - cnt;
        float di = pf_di;
        // issue next node's metadata loads now; they complete during the gather
        int nn = n + stride;
        if (nn < NN) {
            pf_cnt = degi[nn];
            pf_end = offsets[nn];
            pf_pref = partial_pref[nn >> 8];
            pf_di = dinv[nn];
        }
        float ax = 0.f, ay = 0.f;
        if (half == 0) {
            unsigned int u = hw32[n * 32 + c2];
            float sc = di * di;
            ax = bf2f((unsigned short)(u & 0xffffu)) * sc + b0;
            ay = bf2f((unsigned short)(u >> 16)) * sc + b1v;
        }
        for (int base = 0; base < cnt; base += 64) {
            int m = min(64, cnt - base);
            int2 rec = make_int2(0, 0);  // coef bits 0 -> 0.0f
            if (lane < m) rec = sorted[start + base + lane];
            int k = 0;
            for (; k + 16 <= m; k += 16) {
                int e0 = k + half, e1 = k + 2 + half, e2 = k + 4 + half, e3 = k + 6 + half;
                int e4 = k + 8 + half, e5 = k + 10 + half, e6 = k + 12 + half, e7 = k + 14 + half;
                int s0 = __shfl(rec.x, e0), s1 = __shfl(rec.x, e1);
                int s2 = __shfl(rec.x, e2), s3 = __shfl(rec.x, e3);
                int s4 = __shfl(rec.x, e4), s5 = __shfl(rec.x, e5);
                int s6 = __shfl(rec.x, e6), s7 = __shfl(rec.x, e7);
                unsigned int u0 = hw32[s0 * 32 + c2];
                unsigned int u1 = hw32[s1 * 32 + c2];
                unsigned int u2 = hw32[s2 * 32 + c2];
                unsigned int u3 = hw32[s3 * 32 + c2];
                unsigned int u4 = hw32[s4 * 32 + c2];
                unsigned int u5 = hw32[s5 * 32 + c2];
                unsigned int u6 = hw32[s6 * 32 + c2];
                unsigned int u7 = hw32[s7 * 32 + c2];
                float c0 = __int_as_float(__shfl(rec.y, e0));
                float c1 = __int_as_float(__shfl(rec.y, e1));
                float c2f = __int_as_float(__shfl(rec.y, e2));
                float c3 = __int_as_float(__shfl(rec.y, e3));
                float c4 = __int_as_float(__shfl(rec.y, e4));
                float c5 = __int_as_float(__shfl(rec.y, e5));
                float c6 = __int_as_float(__shfl(rec.y, e6));
                float c7 = __int_as_float(__shfl(rec.y, e7));
                ax += bf2f((unsigned short)(u0 & 0xffffu)) * c0;
                ay += bf2f((unsigned short)(u0 >> 16)) * c0;
                ax += bf2f((unsigned short)(u1 & 0xffffu)) * c1;
                ay += bf2f((unsigned short)(u1 >> 16)) * c1;
                ax += bf2f((unsigned short)(u2 & 0xffffu)) * c2f;
                ay += bf2f((unsigned short)(u2 >> 16)) * c2f;
                ax += bf2f((unsigned short)(u3 & 0xffffu)) * c3;
                ay += bf2f((unsigned short)(u3 >> 16)) * c3;
                ax += bf2f((unsigned short)(u4 & 0xffffu)) * c4;
                ay += bf2f((unsigned short)(u4 >> 16)) * c4;
                ax += bf2f((unsigned short)(u5 & 0xffffu)) * c5;
                ay += bf2f((unsigned short)(u5 >> 16)) * c5;
                ax += bf2f((unsigned short)(u6 & 0xffffu)) * c6;
                ay += bf2f((unsigned short)(u6 >> 16)) * c6;
                ax += bf2f((unsigned short)(u7 & 0xffffu)) * c7;
                ay += bf2f((unsigned short)(u7 >> 16)) * c7;
            }
            for (; k + 4 <= m; k += 4) {
                int e0 = k + half, e1 = k + 2 + half;
                int s0 = __shfl(rec.x, e0), s1 = __shfl(rec.x, e1);
                unsigned int u0 = hw32[s0 * 32 + c2];
                unsigned int u1 = hw32[s1 * 32 + c2];
                float c0 = __int_as_float(__shfl(rec.y, e0));
                float c1 = __int_as_float(__shfl(rec.y, e1));
                ax += bf2f((unsigned short)(u0 & 0xffffu)) * c0;
                ay += bf2f((unsigned short)(u0 >> 16)) * c0;
                ax += bf2f((unsigned short)(u1 & 0xffffu)) * c1;
                ay += bf2f((unsigned short)(u1 >> 16)) * c1;
            }
            for (; k < m; k += 2) {
                int e = k + half;  // e may reach m (<64): rec there is (0,0) -> adds 0
                int s = __shfl(rec.x, e);
                float cf = __int_as_float(__shfl(rec.y, e));
                unsigned int u = hw32[s * 32 + c2];
                ax += bf2f((unsigned short)(u & 0xffffu)) * cf;
                ay += bf2f((unsigned short)(u >> 16)) * cf;
            }
        }
        ax += __shfl_xor(ax, 32);
        ay += __shfl_xor(ay, 32);
        if (half == 0) {
            float2 v = make_float2(ax, ay);
            *(float2*)&agg[n * 64 + 2 * c2] = v;
            bsx += ax;
            bsy += ay;
            bqx += ax * ax;
            bqy += ay * ay;
        }
    }
    __shared__ float red[2][4][64];
    if (half == 0) {
        red[0][w][2 * c2] = bsx;
        red[0][w][2 * c2 + 1] = bsy;
        red[1][w][2 * c2] = bqx;
        red[1][w][2 * c2 + 1] = bqy;
    }
    __syncthreads();
    if (w == 0) {
        int c = t;  // 0..63
        float s = red[0][0][c] + red[0][1][c] + red[0][2][c] + red[0][3][c];
        float ss = red[1][0][c] + red[1][1][c] + red[1][2][c] + red[1][3][c];
        atomicAdd(&stats[c], s);
        atomicAdd(&stats[64 + c], ss);
    }
}

// ================= classifier: relu(BN(agg)@W1+b1)@W2 + b2, BN fused =========
__global__ __launch_bounds__(256) void classifier(const float* __restrict__ agg,
                                                  const float* __restrict__ stats,
                                                  const float* __restrict__ gamma,
                                                  const float* __restrict__ beta,
                                                  const float* __restrict__ W1,
                                                  const float* __restrict__ b1,
                                                  const float* __restrict__ W2,
                                                  const float* __restrict__ b2,
                                                  float* __restrict__ out) {
    __shared__ float W1s[2048];
    __shared__ float b1s[32];
    __shared__ float W2s[32];
    __shared__ float scale[64], shift[64];
    int t = threadIdx.x;
    for (int i = t; i < 2048; i += 256) W1s[i] = W1[i];
    if (t < 32) {
        b1s[t] = b1[t];
        W2s[t] = W2[t];
    }
    if (t < 64) {
        const float invN = 1.0f / (float)NN;
        float mean = stats[t] * invN;
        float var = stats[64 + t] * invN - mean * mean;
        float rstd = rsqrtf(var + EPSV);
        float sc = gamma[t] * rstd;
        scale[t] = sc;
        shift[t] = beta[t] - mean * sc;
    }
    __syncthreads();
    int n = blockIdx.x * 256 + t;
    if (n >= NN) return;
    float4 h4[16];
    const float4* hp = (const float4*)(agg + n * 64);
#pragma unroll
    for (int i = 0; i < 16; ++i) h4[i] = hp[i];
    float* hr = (float*)h4;
#pragma unroll
    for (int k = 0; k < 64; ++k) hr[k] = fmaxf(hr[k] * scale[k] + shift[k], 0.f);
    float o = b2[0];
    for (int c = 0; c < 32; ++c) {
        float z = b1s[c];
#pragma unroll
        for (int k = 0; k < 64; ++k) z += hr[k] * W1s[k * 32 + c];
        o += fmaxf(z, 0.f) * W2s[c];
    }
    out[n] = o;
}

extern "C" void kernel_launch(void* const* d_in, const int* in_sizes, int n_in,
                              void* d_out, int out_size, void* d_ws, size_t ws_size,
                              hipStream_t stream) {
    const float* x    = (const float*)d_in[0];
    const int*   ei   = (const int*)d_in[1];
    const float* Win  = (const float*)d_in[2];
    const float* bin  = (const float*)d_in[3];
    const float* cW   = (const float*)d_in[4];
    const float* cb   = (const float*)d_in[5];
    const float* gam  = (const float*)d_in[6];
    const float* bet  = (const float*)d_in[7];
    const float* W1   = (const float*)d_in[8];
    const float* b1   = (const float*)d_in[9];
    const float* W2   = (const float*)d_in[10];
    const float* b2   = (const float*)d_in[11];
    float* out = (float*)d_out;

    // ---- workspace layout ----
    unsigned short* hw = (unsigned short*)d_ws;          // NN*64 bf16 (= NN*32 floats)
    float* agg   = (float*)d_ws + NN * 32;               // NN*64 fp32
    float* dinv  = agg + NN * 64;                        // NN
    float* stats = dinv + NN;                            // 3*128
    int*  degi        = (int*)(stats + 3 * 128);         // NN
    int*  offsets     = degi + NN;                       // NN
    int2* sorted      = (int2*)(offsets + NN);           // EE int2
    int*  partial     = (int*)(sorted + EE);             // 512
    int*  partial_pref = partial + 512;                  // 512
    int*  degi8       = partial_pref + 512;              // 8*NN

    const int* src = ei;
    const int* dst = ei + EE;

    const int NB = (NN + 255) / 256;  // 391
    const int EB = (EE + 255) / 256;  // 6250

    (void)hipMemsetAsync(degi8, 0, 8 * NN * sizeof(int), stream);

    deg_kernel<<<EB, 256, 0, stream>>>(dst, degi8);
    scan1<<<NB, 256, 0, stream>>>(degi8, degi, offsets, partial, dinv);
    scan2<<<1, 512, 0, stream>>>(partial, partial_pref, NB, stats);
    fill_kernel<<<EB * 8, 256, 0, stream>>>(src, dst, offsets, partial_pref, dinv, sorted);

    for (int i = 0; i < 3; ++i) {
        gemm64_bn<<<(NN + 63) / 64, 256, 0, stream>>>(
            agg, x, Win, bin, stats + (i - 1) * 128, gam + (i - 1) * 64,
            bet + (i - 1) * 64, cW + i * 4096, hw, i > 0 ? 1 : 0);
        agg_kernel<<<2048, 256, 0, stream>>>((const unsigned int*)hw, sorted, offsets,
                                             partial_pref, degi, dinv, cb + i * 64, agg,
                                             stats + i * 128);
    }

    classifier<<<(NN + 255) / 256, 256, 0, stream>>>(agg, stats + 2 * 128, gam + 2 * 64,
                                                     bet + 2 * 64, W1, b1, W2, b2, out);
}

// Round 20
// 524.878 us; speedup vs baseline: 1.0813x; 1.0813x over previous
//
#include <hip/hip_runtime.h>

#define NN 100000
#define EE 1600000
#define EPSV 1e-5f
#define QW 12500  // nodes per XCD stripe (8 * 12500 = 100000)

using short8 = __attribute__((ext_vector_type(8))) short;
using floatx4 = __attribute__((ext_vector_type(4))) float;

// fp32 -> bf16 round-to-nearest-even
__device__ __forceinline__ unsigned short f2bf(float f) {
    union { float f; unsigned int u; } cv;
    cv.f = f;
    unsigned int u = cv.u;
    u += 0x7FFFu + ((u >> 16) & 1u);
    return (unsigned short)(u >> 16);
}

__device__ __forceinline__ float bf2f(unsigned short u) {
    union { unsigned int i; float f; } cv;
    cv.i = ((unsigned int)u) << 16;
    return cv.f;
}

// ================= degree histogram: per-XCD private copies ===================
__global__ void deg_kernel(const int* __restrict__ dst, int* __restrict__ degi8) {
    int e = blockIdx.x * 256 + threadIdx.x;
    if (e >= EE) return;
    int q = blockIdx.x & 7;
    atomicAdd(&degi8[q * NN + dst[e]], 1);
}

// ================= scan1: sum 8 histogram copies + dinv + block-local prefix ==
__global__ void scan1(const int* __restrict__ degi8, int* __restrict__ degi,
                      int* __restrict__ offsets, int* __restrict__ partial,
                      float* __restrict__ dinv) {
    __shared__ int sdata[256];
    int t = threadIdx.x;
    int n = blockIdx.x * 256 + t;
    int v = 0;
    if (n < NN) {
#pragma unroll
        for (int q = 0; q < 8; ++q) v += degi8[q * NN + n];
        degi[n] = v;
        dinv[n] = rsqrtf((float)v + 1.0f);
    }
    sdata[t] = v;
    __syncthreads();
    for (int off = 1; off < 256; off <<= 1) {
        int x = (t >= off) ? sdata[t - off] : 0;
        __syncthreads();
        sdata[t] += x;
        __syncthreads();
    }
    if (n < NN) offsets[n] = sdata[t] - v;  // block-local exclusive
    if (t == 255) partial[blockIdx.x] = sdata[255];
}

// ================= scan2 + fused stats zeroing ================================
__global__ void scan2(int* __restrict__ partial, int* __restrict__ partial_pref,
                      int nparts, float* __restrict__ stats) {
    __shared__ int sdata[512];
    int t = threadIdx.x;
    if (t < 384) stats[t] = 0.f;  // zero 3 layers x 128 stats (fused memset)
    int v = (t < nparts) ? partial[t] : 0;
    sdata[t] = v;
    __syncthreads();
    for (int off = 1; off < 512; off <<= 1) {
        int x = (t >= off) ? sdata[t - off] : 0;
        __syncthreads();
        sdata[t] += x;
        __syncthreads();
    }
    if (t < nparts) partial_pref[t] = sdata[t] - v;  // exclusive
}

// ================= CSR fill, XCD-sharded by dst range =========================
__global__ void fill_kernel(const int* __restrict__ src, const int* __restrict__ dst,
                            int* __restrict__ offsets,
                            const int* __restrict__ partial_pref,
                            const float* __restrict__ dinv,
                            int2* __restrict__ sorted) {
    int q = blockIdx.x & 7;
    int e = (blockIdx.x >> 3) * 256 + threadIdx.x;
    if (e >= EE) return;
    int d = dst[e];
    if ((unsigned)(d - q * QW) >= (unsigned)QW) return;
    int s = src[e];
    int idx = partial_pref[d >> 8] + atomicAdd(&offsets[d], 1);
    int2 rec;
    rec.x = s;
    rec.y = __float_as_int(dinv[s] * dinv[d]);
    sorted[idx] = rec;
}

// ================= hw(bf16) = act(in) @ W via MFMA bf16 ======================
__global__ __launch_bounds__(256) void gemm64_bn(const float* __restrict__ in,
                                                 const float* __restrict__ x,
                                                 const float* __restrict__ Win,
                                                 const float* __restrict__ bin,
                                                 const float* __restrict__ stats,
                                                 const float* __restrict__ gamma,
                                                 const float* __restrict__ beta,
                                                 const float* __restrict__ W,
                                                 unsigned short* __restrict__ out,
                                                 int mode) {
    __shared__ __align__(16) unsigned short As[64 * 72];
    __shared__ __align__(16) unsigned short Wt[64 * 72];
    __shared__ float scale[64], shift[64];
    __shared__ float Wins[320];
    __shared__ float bins[64];
    int t = threadIdx.x;
    if (mode == 1) {
        if (t < 64) {
            const float invN = 1.0f / (float)NN;
            float mean = stats[t] * invN;
            float var = stats[64 + t] * invN - mean * mean;
            float rstd = rsqrtf(var + EPSV);
            float sc = gamma[t] * rstd;
            scale[t] = sc;
            shift[t] = beta[t] - mean * sc;
        }
    } else {
        for (int i = t; i < 320; i += 256) Wins[i] = Win[i];
        if (t < 64) bins[t] = bin[t];
    }
    // W^T -> LDS bf16: Wt[c][k] = W[k][c]
    for (int i = t; i < 4096; i += 256) {
        int k = i >> 6, c = i & 63;
        Wt[c * 72 + k] = f2bf(W[k * 64 + c]);
    }
    __syncthreads();
    int base = blockIdx.x * 64;
    if (mode == 1) {
        for (int i = t; i < 4096; i += 256) {
            int r = i >> 6, c = i & 63;
            float v = 0.f;
            if (base + r < NN) {
                v = in[(base + r) * 64 + c];
                v = fmaxf(v * scale[c] + shift[c], 0.f);
            }
            As[r * 72 + c] = f2bf(v);
        }
    } else {
        for (int i = t; i < 4096; i += 256) {
            int r = i >> 6, c = i & 63;
            int n = base + r;
            float v = 0.f;
            if (n < NN) {
                float acc = bins[c];
#pragma unroll
                for (int k = 0; k < 5; ++k) acc += x[n * 5 + k] * Wins[k * 64 + c];
                v = fmaxf(acc, 0.f);
            }
            As[r * 72 + c] = f2bf(v);
        }
    }
    __syncthreads();
    int wv = t >> 6;
    int lane = t & 63;
    int quad = lane >> 4;
    int mm = lane & 15;
    short8 a0 = *(const short8*)&As[(wv * 16 + mm) * 72 + quad * 8];
    short8 a1 = *(const short8*)&As[(wv * 16 + mm) * 72 + 32 + quad * 8];
#pragma unroll
    for (int ct = 0; ct < 4; ++ct) {
        short8 b0 = *(const short8*)&Wt[(ct * 16 + mm) * 72 + quad * 8];
        short8 b1 = *(const short8*)&Wt[(ct * 16 + mm) * 72 + 32 + quad * 8];
        floatx4 acc = {0.f, 0.f, 0.f, 0.f};
        acc = __builtin_amdgcn_mfma_f32_16x16x32_bf16(a0, b0, acc, 0, 0, 0);
        acc = __builtin_amdgcn_mfma_f32_16x16x32_bf16(a1, b1, acc, 0, 0, 0);
#pragma unroll
        for (int reg = 0; reg < 4; ++reg) {
            int n = base + wv * 16 + quad * 4 + reg;
            if (n < NN) out[n * 64 + ct * 16 + mm] = f2bf(acc[reg]);
        }
    }
}

// ================= CSR gather aggregation, 2 edges/wave, packed bf16x2 ========
__global__ __launch_bounds__(256) void agg_kernel(const unsigned int* __restrict__ hw32,
                                                  const int2* __restrict__ sorted,
                                                  const int* __restrict__ offsets,
                                                  const int* __restrict__ partial_pref,
                                                  const int* __restrict__ degi,
                                                  const float* __restrict__ dinv,
                                                  const float* __restrict__ b,
                                                  float* __restrict__ agg,
                                                  float* __restrict__ stats) {
    int t = threadIdx.x;
    int lane = t & 63;
    int w = t >> 6;
    int half = lane >> 5;
    int c2 = lane & 31;  // channel pair: 2*c2, 2*c2+1
    float b0 = b[2 * c2], b1v = b[2 * c2 + 1];
    float bsx = 0.f, bsy = 0.f, bqx = 0.f, bqy = 0.f;
    for (int n = blockIdx.x * 4 + w; n < NN; n += gridDim.x * 4) {
        int cnt = degi[n];
        int start = partial_pref[n >> 8] + offsets[n] - cnt;  // offsets is local_excl+cnt
        float di = dinv[n];
        float ax = 0.f, ay = 0.f;
        if (half == 0) {
            unsigned int u = hw32[n * 32 + c2];
            float sc = di * di;
            ax = bf2f((unsigned short)(u & 0xffffu)) * sc + b0;
            ay = bf2f((unsigned short)(u >> 16)) * sc + b1v;
        }
        for (int base = 0; base < cnt; base += 64) {
            int m = min(64, cnt - base);
            int2 rec = make_int2(0, 0);  // coef bits 0 -> 0.0f
            if (lane < m) rec = sorted[start + base + lane];
            int k = 0;
            for (; k + 16 <= m; k += 16) {
                int e0 = k + half, e1 = k + 2 + half, e2 = k + 4 + half, e3 = k + 6 + half;
                int e4 = k + 8 + half, e5 = k + 10 + half, e6 = k + 12 + half, e7 = k + 14 + half;
                int s0 = __shfl(rec.x, e0), s1 = __shfl(rec.x, e1);
                int s2 = __shfl(rec.x, e2), s3 = __shfl(rec.x, e3);
                int s4 = __shfl(rec.x, e4), s5 = __shfl(rec.x, e5);
                int s6 = __shfl(rec.x, e6), s7 = __shfl(rec.x, e7);
                unsigned int u0 = hw32[s0 * 32 + c2];
                unsigned int u1 = hw32[s1 * 32 + c2];
                unsigned int u2 = hw32[s2 * 32 + c2];
                unsigned int u3 = hw32[s3 * 32 + c2];
                unsigned int u4 = hw32[s4 * 32 + c2];
                unsigned int u5 = hw32[s5 * 32 + c2];
                unsigned int u6 = hw32[s6 * 32 + c2];
                unsigned int u7 = hw32[s7 * 32 + c2];
                float c0 = __int_as_float(__shfl(rec.y, e0));
                float c1 = __int_as_float(__shfl(rec.y, e1));
                float c2f = __int_as_float(__shfl(rec.y, e2));
                float c3 = __int_as_float(__shfl(rec.y, e3));
                float c4 = __int_as_float(__shfl(rec.y, e4));
                float c5 = __int_as_float(__shfl(rec.y, e5));
                float c6 = __int_as_float(__shfl(rec.y, e6));
                float c7 = __int_as_float(__shfl(rec.y, e7));
                ax += bf2f((unsigned short)(u0 & 0xffffu)) * c0;
                ay += bf2f((unsigned short)(u0 >> 16)) * c0;
                ax += bf2f((unsigned short)(u1 & 0xffffu)) * c1;
                ay += bf2f((unsigned short)(u1 >> 16)) * c1;
                ax += bf2f((unsigned short)(u2 & 0xffffu)) * c2f;
                ay += bf2f((unsigned short)(u2 >> 16)) * c2f;
                ax += bf2f((unsigned short)(u3 & 0xffffu)) * c3;
                ay += bf2f((unsigned short)(u3 >> 16)) * c3;
                ax += bf2f((unsigned short)(u4 & 0xffffu)) * c4;
                ay += bf2f((unsigned short)(u4 >> 16)) * c4;
                ax += bf2f((unsigned short)(u5 & 0xffffu)) * c5;
                ay += bf2f((unsigned short)(u5 >> 16)) * c5;
                ax += bf2f((unsigned short)(u6 & 0xffffu)) * c6;
                ay += bf2f((unsigned short)(u6 >> 16)) * c6;
                ax += bf2f((unsigned short)(u7 & 0xffffu)) * c7;
                ay += bf2f((unsigned short)(u7 >> 16)) * c7;
            }
            for (; k + 4 <= m; k += 4) {
                int e0 = k + half, e1 = k + 2 + half;
                int s0 = __shfl(rec.x, e0), s1 = __shfl(rec.x, e1);
                unsigned int u0 = hw32[s0 * 32 + c2];
                unsigned int u1 = hw32[s1 * 32 + c2];
                float c0 = __int_as_float(__shfl(rec.y, e0));
                float c1 = __int_as_float(__shfl(rec.y, e1));
                ax += bf2f((unsigned short)(u0 & 0xffffu)) * c0;
                ay += bf2f((unsigned short)(u0 >> 16)) * c0;
                ax += bf2f((unsigned short)(u1 & 0xffffu)) * c1;
                ay += bf2f((unsigned short)(u1 >> 16)) * c1;
            }
            for (; k < m; k += 2) {
                int e = k + half;  // e may reach m (<64): rec there is (0,0) -> adds 0
                int s = __shfl(rec.x, e);
                float cf = __int_as_float(__shfl(rec.y, e));
                unsigned int u = hw32[s * 32 + c2];
                ax += bf2f((unsigned short)(u & 0xffffu)) * cf;
                ay += bf2f((unsigned short)(u >> 16)) * cf;
            }
        }
        ax += __shfl_xor(ax, 32);
        ay += __shfl_xor(ay, 32);
        if (half == 0) {
            float2 v = make_float2(ax, ay);
            *(float2*)&agg[n * 64 + 2 * c2] = v;
            bsx += ax;
            bsy += ay;
            bqx += ax * ax;
            bqy += ay * ay;
        }
    }
    __shared__ float red[2][4][64];
    if (half == 0) {
        red[0][w][2 * c2] = bsx;
        red[0][w][2 * c2 + 1] = bsy;
        red[1][w][2 * c2] = bqx;
        red[1][w][2 * c2 + 1] = bqy;
    }
    __syncthreads();
    if (w == 0) {
        int c = t;  // 0..63
        float s = red[0][0][c] + red[0][1][c] + red[0][2][c] + red[0][3][c];
        float ss = red[1][0][c] + red[1][1][c] + red[1][2][c] + red[1][3][c];
        atomicAdd(&stats[c], s);
        atomicAdd(&stats[64 + c], ss);
    }
}

// ================= classifier: relu(BN(agg)@W1+b1)@W2 + b2, BN fused =========
__global__ __launch_bounds__(256) void classifier(const float* __restrict__ agg,
                                                  const float* __restrict__ stats,
                                                  const float* __restrict__ gamma,
                                                  const float* __restrict__ beta,
                                                  const float* __restrict__ W1,
                                                  const float* __restrict__ b1,
                                                  const float* __restrict__ W2,
                                                  const float* __restrict__ b2,
                                                  float* __restrict__ out) {
    __shared__ float W1s[2048];
    __shared__ float b1s[32];
    __shared__ float W2s[32];
    __shared__ float scale[64], shift[64];
    int t = threadIdx.x;
    for (int i = t; i < 2048; i += 256) W1s[i] = W1[i];
    if (t < 32) {
        b1s[t] = b1[t];
        W2s[t] = W2[t];
    }
    if (t < 64) {
        const float invN = 1.0f / (float)NN;
        float mean = stats[t] * invN;
        float var = stats[64 + t] * invN - mean * mean;
        float rstd = rsqrtf(var + EPSV);
        float sc = gamma[t] * rstd;
        scale[t] = sc;
        shift[t] = beta[t] - mean * sc;
    }
    __syncthreads();
    int n = blockIdx.x * 256 + t;
    if (n >= NN) return;
    float4 h4[16];
    const float4* hp = (const float4*)(agg + n * 64);
#pragma unroll
    for (int i = 0; i < 16; ++i) h4[i] = hp[i];
    float* hr = (float*)h4;
#pragma unroll
    for (int k = 0; k < 64; ++k) hr[k] = fmaxf(hr[k] * scale[k] + shift[k], 0.f);
    float o = b2[0];
    for (int c = 0; c < 32; ++c) {
        float z = b1s[c];
#pragma unroll
        for (int k = 0; k < 64; ++k) z += hr[k] * W1s[k * 32 + c];
        o += fmaxf(z, 0.f) * W2s[c];
    }
    out[n] = o;
}

extern "C" void kernel_launch(void* const* d_in, const int* in_sizes, int n_in,
                              void* d_out, int out_size, void* d_ws, size_t ws_size,
                              hipStream_t stream) {
    const float* x    = (const float*)d_in[0];
    const int*   ei   = (const int*)d_in[1];
    const float* Win  = (const float*)d_in[2];
    const float* bin  = (const float*)d_in[3];
    const float* cW   = (const float*)d_in[4];
    const float* cb   = (const float*)d_in[5];
    const float* gam  = (const float*)d_in[6];
    const float* bet  = (const float*)d_in[7];
    const float* W1   = (const float*)d_in[8];
    const float* b1   = (const float*)d_in[9];
    const float* W2   = (const float*)d_in[10];
    const float* b2   = (const float*)d_in[11];
    float* out = (float*)d_out;

    // ---- workspace layout ----
    unsigned short* hw = (unsigned short*)d_ws;          // NN*64 bf16 (= NN*32 floats)
    float* agg   = (float*)d_ws + NN * 32;               // NN*64 fp32
    float* dinv  = agg + NN * 64;                        // NN
    float* stats = dinv + NN;                            // 3*128
    int*  degi        = (int*)(stats + 3 * 128);         // NN
    int*  offsets     = degi + NN;                       // NN
    int2* sorted      = (int2*)(offsets + NN);           // EE int2
    int*  partial     = (int*)(sorted + EE);             // 512
    int*  partial_pref = partial + 512;                  // 512
    int*  degi8       = partial_pref + 512;              // 8*NN

    const int* src = ei;
    const int* dst = ei + EE;

    const int NB = (NN + 255) / 256;  // 391
    const int EB = (EE + 255) / 256;  // 6250

    (void)hipMemsetAsync(degi8, 0, 8 * NN * sizeof(int), stream);

    deg_kernel<<<EB, 256, 0, stream>>>(dst, degi8);
    scan1<<<NB, 256, 0, stream>>>(degi8, degi, offsets, partial, dinv);
    scan2<<<1, 512, 0, stream>>>(partial, partial_pref, NB, stats);
    fill_kernel<<<EB * 8, 256, 0, stream>>>(src, dst, offsets, partial_pref, dinv, sorted);

    for (int i = 0; i < 3; ++i) {
        gemm64_bn<<<(NN + 63) / 64, 256, 0, stream>>>(
            agg, x, Win, bin, stats + (i - 1) * 128, gam + (i - 1) * 64,
            bet + (i - 1) * 64, cW + i * 4096, hw, i > 0 ? 1 : 0);
        agg_kernel<<<2048, 256, 0, stream>>>((const unsigned int*)hw, sorted, offsets,
                                             partial_pref, degi, dinv, cb + i * 64, agg,
                                             stats + i * 128);
    }

    classifier<<<(NN + 255) / 256, 256, 0, stream>>>(agg, stats + 2 * 128, gam + 2 * 64,
                                                     bet + 2 * 64, W1, b1, W2, b2, out);
}